// Round 15
// baseline (160.534 us; speedup 1.0000x reference)
//
#include <hip/hip_runtime.h>
#include <hip/hip_bf16.h>
#include <math.h>

// TriangleAttention — round 21: half-slab blocks. r19/r20 refuted TLP-via-
// wider-blocks (8-wave: phase idleness + 8-wave barriers, 70 µs vs r18's 64).
// This round raises BLOCK COUNT instead: grid 1024 = (bl, half), 4-wave
// blocks, r18's body. Each block: LN all 256 slab rows (1/thread — K/V needs
// them; 2x duplicated across halves, ~3 µs of parallel work), stage K/V for
// all 256 keys, but Q/attention/Wo only for its own 128 query rows -> per-wave
// attention work HALVED (512 exps vs 1024), 3 blocks/CU resident (LDS 51.5 KB).
// All waves active in every phase; out rows disjoint per block.
// Q-fragments read cross-wave znl slices -> one barrier after LN (new vs r18).
// bl=b&511, hb=b>>9: both halves of a slab land on the same XCD (512%8==0) ->
// duplicated z reads are L2 hits.
// HAZARD RULES (r10-r14): inline asm never reads an MFMA dest directly — a
// compiler VALU op in between (s*L2E mul / ag+bg add / lacc add+mul / aq*QS)
// absorbs the wait-states. BAN LIST (r7-8): __builtin_amdgcn_exp2f/rcpf;
// __launch_bounds__ 2nd arg >= 4 (64-VGPR clamp, r7+r19).
// CANARY: VGPR <= 128, WRITE ~33 MB (spill), absmax exactly 0.0078125.
// B=2, L=256, D=64, H=4, Dh=16.
//
// 16x16x32 layouts (verified r2-5):  A[m=lane&15][k=quad*8+u],
//   B[k=quad*8+u][n=lane&15], C/D: col=lane&15, row=quad*4+reg.
// 16x16x16 layouts (verified r14): A[m=lane&15][k=quad*4+u],
//   B[k=quad*4+u][n=lane&15], C/D identical to above.

typedef __attribute__((ext_vector_type(4))) float f32x4;
typedef __attribute__((ext_vector_type(8))) short s16x8;
typedef __attribute__((ext_vector_type(4))) short s16x4;

#define MFMA16(a, b, c) __builtin_amdgcn_mfma_f32_16x16x32_bf16((a), (b), (c), 0, 0, 0)

__device__ __forceinline__ f32x4 mfma16b(s16x4 a, s16x4 b, f32x4 c) {
#if __has_builtin(__builtin_amdgcn_mfma_f32_16x16x16bf16_1k)
    return __builtin_amdgcn_mfma_f32_16x16x16bf16_1k(a, b, c, 0, 0, 0);
#elif __has_builtin(__builtin_amdgcn_mfma_f32_16x16x16_bf16)
    return __builtin_amdgcn_mfma_f32_16x16x16_bf16(a, b, c, 0, 0, 0);
#else
    f32x4 d;
    asm volatile("s_nop 1\n\t"
                 "v_mfma_f32_16x16x16_bf16 %0, %1, %2, %3\n\t"
                 "s_nop 7\n\t"
                 "s_nop 7"
                 : "=v"(d) : "v"(a), "v"(b), "v"(c));
    return d;
#endif
}

__device__ __forceinline__ float exp2a(float x) {   // raw v_exp_f32 (input MUST
    float r;                                        // be VALU-produced, not MFMA)
    asm("v_exp_f32 %0, %1" : "=v"(r) : "v"(x));
    return r;
}
__device__ __forceinline__ float rcpa(float x) {    // raw v_rcp_f32 (same rule)
    float r;
    asm("v_rcp_f32 %0, %1" : "=v"(r) : "v"(x));
    return r;
}

__device__ __forceinline__ unsigned pk2(float a, float b) {   // 2xf32 -> packed bf16x2 (RNE)
    union { __hip_bfloat162 h; unsigned u; } c;
    float2 t; t.x = a; t.y = b;
    c.h = __float22bfloat162_rn(t);
    return c.u;
}
__device__ __forceinline__ s16x8 cvt8(const float* p) {  // 8 fp32 -> bf16x8
    union { unsigned u[4]; s16x8 v; } r;
    r.u[0] = pk2(p[0], p[1]); r.u[1] = pk2(p[2], p[3]);
    r.u[2] = pk2(p[4], p[5]); r.u[3] = pk2(p[6], p[7]);
    return r.v;
}
__device__ __forceinline__ s16x4 cvt4(const float* p) {  // 4 fp32 -> bf16x4
    union { unsigned u[2]; s16x4 v; } r;
    r.u[0] = pk2(p[0], p[1]); r.u[1] = pk2(p[2], p[3]);
    return r.v;
}

// LDS map (shorts).
//   ZNL: LN'd slab rows; global row R at (R>>6)*4096 + ((R>>4)&3)*1024 +
//        (R&15)*64, gq-swizzled (r6-verified layout).
//   KSH [256 pos][20 sh pad] b64 frags; VT [16 dh][264 pos-pad].
static constexpr int ZNL = 0;          // 16384 sh
static constexpr int KSH = 16384;      // 5120 sh
static constexpr int VT  = 21504;      // 4224 sh
static constexpr int LDS_EL = 25728;   // 51456 B -> 3 blocks/CU

__global__ __launch_bounds__(256, 3)
void ka_half(const float* __restrict__ z, const float* __restrict__ ln_s,
             const float* __restrict__ ln_b, const float* __restrict__ Wq,
             const float* __restrict__ Wk, const float* __restrict__ Wv,
             const float* __restrict__ Wg, const float* __restrict__ bg,
             const float* __restrict__ Wo, const float* __restrict__ bo,
             float* __restrict__ out)
{
    __shared__ __align__(16) short lds[LDS_EL];
    const int tid = threadIdx.x, lane = tid & 63, w = tid >> 6;
    const int n16 = lane & 15, quad = lane >> 4;
    const int b = blockIdx.x, bl = b & 511, hb = b >> 9;   // halves share XCD
    const int wsl = w * 4096;                      // K/V staging slice (rows w*64..)

    // ---- LN all 256 slab rows, 1/thread (identical math to r18) ----
    {
        float zn[64];
        const float4* zp4 = (const float4*)(z + ((size_t)bl * 256 + tid) * 64);
        #pragma unroll
        for (int gq = 0; gq < 16; ++gq) {
            float4 v4 = zp4[gq];
            zn[gq * 4 + 0] = v4.x; zn[gq * 4 + 1] = v4.y;
            zn[gq * 4 + 2] = v4.z; zn[gq * 4 + 3] = v4.w;
        }
        float mu = 0.f;
        #pragma unroll
        for (int k = 0; k < 64; ++k) mu += zn[k];
        mu *= (1.f / 64.f);
        float va = 0.f;
        #pragma unroll
        for (int k = 0; k < 64; ++k) { float d = zn[k] - mu; va += d * d; }
        const float rs = rsqrtf(va * (1.f / 64.f) + 1e-5f);
        #pragma unroll
        for (int k = 0; k < 64; ++k) zn[k] = (zn[k] - mu) * rs * ln_s[k] + ln_b[k];
        const int lr = lane;
        #pragma unroll
        for (int gq = 0; gq < 8; ++gq) {
            union { unsigned u[4]; s16x8 v; } pkv;
            pkv.u[0] = pk2(zn[gq * 8 + 0], zn[gq * 8 + 1]);
            pkv.u[1] = pk2(zn[gq * 8 + 2], zn[gq * 8 + 3]);
            pkv.u[2] = pk2(zn[gq * 8 + 4], zn[gq * 8 + 5]);
            pkv.u[3] = pk2(zn[gq * 8 + 6], zn[gq * 8 + 7]);
            *(s16x8*)&lds[ZNL + wsl + (lr >> 4) * 1024 + (lr & 15) * 64
                          + ((gq ^ (lr & 7)) * 8)] = pkv.v;
        }
    }
    __syncthreads();   // znl visible: Q proj reads other waves' slices

    constexpr float QS  = 0.25f;                            // 1/sqrt(Dh); log2e at exp
    constexpr float L2E = 1.44269504088896340736f;
    s16x4 ones4;                                            // bf16 1.0 x4
    {
        union { unsigned u[2]; s16x4 v; } c;
        c.u[0] = 0x3F803F80u; c.u[1] = 0x3F803F80u;
        ones4 = c.v;
    }

    f32x4 acc_out[2][4];                           // [qt][nt], over all 4 heads
    #pragma unroll
    for (int qt = 0; qt < 2; ++qt)
        #pragma unroll
        for (int nt = 0; nt < 4; ++nt) acc_out[qt][nt] = {};

    for (int h = 0; h < 4; ++h) {
        // ---- W head-slice frags ----
        s16x8 bq[2], bk[2], bv[2], bgf[2];
        #pragma unroll
        for (int ks = 0; ks < 2; ++ks) {
            size_t off = (size_t)(h * 16 + n16) * 64 + ks * 32 + quad * 8;
            bq[ks] = cvt8(Wq + off);  bk[ks] = cvt8(Wk + off);
            bv[ks] = cvt8(Wv + off);  bgf[ks] = cvt8(Wg + off);
        }
        const float4 bg4 = *(const float4*)(bg + h * 16 + quad * 4);

        // ---- K/V proj: own slice, all 4 tiles (keys for everyone) ----
        #pragma unroll
        for (int t = 0; t < 4; ++t) {
            s16x8 zn0 = *(const s16x8*)&lds[ZNL + wsl + t * 1024 + n16 * 64
                                            + ((quad ^ (n16 & 7)) * 8)];
            s16x8 zn1 = *(const s16x8*)&lds[ZNL + wsl + t * 1024 + n16 * 64
                                            + (((4 + quad) ^ (n16 & 7)) * 8)];
            f32x4 ak = {}, av = {};
            ak = MFMA16(bk[0], zn0, ak);  ak = MFMA16(bk[1], zn1, ak);   // K^T
            av = MFMA16(zn0, bv[0], av);  av = MFMA16(zn1, bv[1], av);   // V
            {   // K^T -> KSH[pos][dh] (stride 20, conflict-free b64 frags)
                uint2 p = {pk2(ak[0], ak[1]), pk2(ak[2], ak[3])};
                *(uint2*)&lds[KSH + (w * 64 + t * 16 + n16) * 20 + quad * 4] = p;
            }
            {   // V -> VT[dh][pos]
                uint2 p = {pk2(av[0], av[1]), pk2(av[2], av[3])};
                *(uint2*)&lds[VT + n16 * 264 + (w * 64 + t * 16 + quad * 4)] = p;
            }
        }

        // ---- Q/G proj: this block's half, wave's 2 tiles (may cross slices) ----
        float g4t[2][4];
        s16x4 qa4[2];
        #pragma unroll
        for (int qt = 0; qt < 2; ++qt) {
            const int gt = hb * 8 + w * 2 + qt;    // global 16-row tile
            const int base = ZNL + (gt >> 2) * 4096 + (gt & 3) * 1024 + n16 * 64;
            s16x8 zn0 = *(const s16x8*)&lds[base + ((quad ^ (n16 & 7)) * 8)];
            s16x8 zn1 = *(const s16x8*)&lds[base + (((4 + quad) ^ (n16 & 7)) * 8)];
            f32x4 aq = {}, ag = {};
            aq = MFMA16(bq[0], zn0, aq);  aq = MFMA16(bq[1], zn1, aq);   // Q^T
            ag = MFMA16(bgf[0], zn0, ag); ag = MFMA16(bgf[1], zn1, ag);  // G^T
            {   // Q^T (scaled) -> in-register B-frag: Q^T[dh=quad*4+r][i=n16]
                union { unsigned u[2]; s16x4 v; } q;
                q.u[0] = pk2(aq[0] * QS, aq[1] * QS);   // mul absorbs MFMA hazard
                q.u[1] = pk2(aq[2] * QS, aq[3] * QS);
                qa4[qt] = q.v;
            }
            #pragma unroll
            for (int r = 0; r < 4; ++r) {           // gate (row gt*16+n16, dh=q*4+r)
                float x = ag[r] + bg4[r];           // add absorbs MFMA hazard
                g4t[qt][r] = rcpa(1.f + exp2a(x * -L2E));
            }
        }
        __syncthreads();   // KSH/VT for head h visible to all waves

        // ---- attention (16x16x16): S^T = K@Q^T; P in-register; O^T = V^T@P^T;
        //      l = ones@P^T on the matrix pipe ----
        f32x4 o4[2], lacc[2];
        #pragma unroll
        for (int qt = 0; qt < 2; ++qt) { o4[qt] = {}; lacc[qt] = {}; }
        const int kbase = KSH + n16 * 20 + quad * 4;    // + jt*320
        const int vbase = VT + n16 * 264 + quad * 4;    // + jt*16
        for (int ch = 0; ch < 8; ++ch) {                // 32 keys per chunk
            #pragma unroll
            for (int jtl = 0; jtl < 2; ++jtl) {
                const int jt = ch * 2 + jtl;
                s16x4 kf = *(const s16x4*)&lds[kbase + jt * 320];
                s16x4 vf = *(const s16x4*)&lds[vbase + jt * 16];
                #pragma unroll
                for (int qt = 0; qt < 2; ++qt) {
                    f32x4 zc = {};
                    f32x4 s = mfma16b(kf, qa4[qt], zc);  // S^T: reg r = key q*4+r, col i=n16
                    // v_mul absorbs the MFMA->asm hazard.
                    float e0 = exp2a(s[0] * L2E), e1 = exp2a(s[1] * L2E);
                    float e2 = exp2a(s[2] * L2E), e3 = exp2a(s[3] * L2E);
                    union { unsigned u[2]; s16x4 v; } pb;
                    pb.u[0] = pk2(e0, e1); pb.u[1] = pk2(e2, e3);
                    o4[qt]   = mfma16b(vf, pb.v, o4[qt]);      // O^T: col=i, row=dh
                    lacc[qt] = mfma16b(ones4, pb.v, lacc[qt]); // l[i], all rows
                }
            }
        }

        // ---- per-head epilogue: gate+normalize -> bf16 -> Wo MFMA accumulate ----
        s16x4 goB[2];
        #pragma unroll
        for (int qt = 0; qt < 2; ++qt) {
            const float l = (lacc[qt][0] + lacc[qt][1]) * 0.5f;  // VALU ops absorb hazard
            const float inv = rcpa(l);
            float g0 = g4t[qt][0] * o4[qt][0] * inv;
            float g1 = g4t[qt][1] * o4[qt][1] * inv;
            float g2 = g4t[qt][2] * o4[qt][2] * inv;
            float g3 = g4t[qt][3] * o4[qt][3] * inv;
            union { unsigned u[2]; s16x4 v; } pb;
            pb.u[0] = pk2(g0, g1); pb.u[1] = pk2(g2, g3);
            goB[qt] = pb.v;
        }
        #pragma unroll
        for (int nt = 0; nt < 4; ++nt) {
            // Wo A-frag: A[m=outd local=n16][k=dh=quad*4+u] for tile nt, head h
            s16x4 wof = cvt4(Wo + (size_t)(nt * 16 + n16) * 64 + h * 16 + quad * 4);
            #pragma unroll
            for (int qt = 0; qt < 2; ++qt)
                acc_out[qt][nt] = mfma16b(wof, goB[qt], acc_out[qt][nt]);
        }
        __syncthreads();   // KSH/VT reads done before next head's proj writes
    }

    // ---- final store: out = acc + bo; rows hb*128 + w*32 + qt*16 + n16 ----
    #pragma unroll
    for (int nt = 0; nt < 4; ++nt) {
        const float4 b4 = *(const float4*)(bo + nt * 16 + quad * 4);
        f32x4 b4v; b4v[0] = b4.x; b4v[1] = b4.y; b4v[2] = b4.z; b4v[3] = b4.w;
        #pragma unroll
        for (int qt = 0; qt < 2; ++qt) {
            f32x4 v = acc_out[qt][nt] + b4v;   // VALU add absorbs MFMA->store path
            *(f32x4*)&out[((size_t)bl * 256 + hb * 128 + w * 32 + qt * 16 + n16) * 64
                          + nt * 16 + quad * 4] = v;
        }
    }
}

extern "C" void kernel_launch(void* const* d_in, const int* in_sizes, int n_in,
                              void* d_out, int out_size, void* d_ws, size_t ws_size,
                              hipStream_t stream) {
    const float* z  = (const float*)d_in[0];
    const float* ls = (const float*)d_in[1];
    const float* lb = (const float*)d_in[2];
    const float* Wq = (const float*)d_in[3];
    const float* Wk = (const float*)d_in[4];
    const float* Wv = (const float*)d_in[5];
    const float* Wg = (const float*)d_in[6];
    const float* bg = (const float*)d_in[7];
    const float* Wo = (const float*)d_in[8];
    const float* bo = (const float*)d_in[9];
    float* out = (float*)d_out;

    hipLaunchKernelGGL(ka_half, dim3(1024), dim3(256), 0, stream,
                       z, ls, lb, Wq, Wk, Wv, Wg, bg, Wo, bo, out);
}